// Round 1
// 1731.824 us; speedup vs baseline: 1.2297x; 1.2297x over previous
//
#include <hip/hip_runtime.h>

// ---------------- constants ----------------
#define BWIN 2048
#define NKV  49      // kv rows per window
#define DIM  384
#define NH   12
#define HD   32
#define QN   196     // q rows per window
#define KQ   192     // q input width (DIM/CS)
#define SCALE 0.17677669529663687f

// LDS element offsets (u16 elements). One flat array:
//   ks   [49][392]      K all heads, kk-major (col = h*32+d), stride 392 (%8==0, bank-spread)
//   vt   [12][32][72]   per-head V^T [d][kk], kk pad to 72, pad zeroed
//   bias [169][12]      bf16 bias table
//   unionC (phase-overlapped):
//     phase0/1: kvs  [49][392]   kv staged bf16
//     phase2:   qtile[16][200] ; obuf[12][16][40] ; qp[12][16][40] ; P[12][16][72]
#define KS_STR  392
#define VT_STR  72
#define QT_STR  200
#define OB_STR  40
#define QP_STR  40
#define P_STR   72

#define OFF_KS   0
#define OFF_VT   (NKV * KS_STR)                    // 19208
#define OFF_BIAS (OFF_VT + NH * HD * VT_STR)       // 46856
#define OFF_UC   (OFF_BIAS + 169 * NH)             // 48884
#define OFF_QT   OFF_UC                            // 48884 (3200 el)
#define OFF_OB   (OFF_QT + 16 * QT_STR)            // 52084 (7680 el)
#define OFF_QP   (OFF_OB + NH * 16 * OB_STR)       // 59764 (7680 el)
#define OFF_P    (OFF_QP + NH * 16 * QP_STR)       // 67444 (13824 el)
#define LDS_TOT  (OFF_P + NH * 16 * P_STR)         // 81268 el = 162536 B  (<= 163840)

typedef __bf16 bf16x8 __attribute__((ext_vector_type(8)));
typedef float  f32x4  __attribute__((ext_vector_type(4)));
typedef unsigned short u16;
typedef unsigned int   u32;

__device__ __forceinline__ int imin(int a, int b) { return a < b ? a : b; }

__device__ __forceinline__ u16 f2b(float f) {            // fp32 -> bf16 RNE
    u32 u = __builtin_bit_cast(u32, f);
    return (u16)((u + 0x7fffu + ((u >> 16) & 1u)) >> 16);
}
__device__ __forceinline__ float b2f(u16 h) {
    return __builtin_bit_cast(float, ((u32)h) << 16);
}
__device__ __forceinline__ bf16x8 ld_frag(const u16* p) { // 16B frag load (LDS or global)
    uint4 v = *(const uint4*)p;
    return __builtin_bit_cast(bf16x8, v);
}
__device__ __forceinline__ void lds_fence() {
    asm volatile("s_waitcnt lgkmcnt(0)" ::: "memory");
}
#define MFMA(a, b, c) __builtin_amdgcn_mfma_f32_16x16x32_bf16((a), (b), (c), 0, 0, 0)

// ---------------- K0: transpose+convert weights to bf16 in ws ----------------
// ws layout (ushort elems): w_kvT[768][384] @0 ; w_qT[384][192] @294912 ; w_projT[192][384] @368640
__global__ void prep_weights(const float* __restrict__ w_kv, const float* __restrict__ w_q,
                             const float* __restrict__ w_proj, u16* __restrict__ wbuf) {
    int i = blockIdx.x * 512 + threadIdx.x;   // grid covers exactly 442368
    if (i < 294912) {
        int n = i / 384, k = i % 384;
        wbuf[i] = f2b(w_kv[k * 768 + n]);
    } else if (i < 368640) {
        int j = i - 294912;
        int n = j / 192, k = j % 192;
        wbuf[i] = f2b(w_q[k * 384 + n]);
    } else {
        int j = i - 368640;
        int n = j / 384, k = j % 384;
        wbuf[i] = f2b(w_proj[k * 192 + n]);
    }
}

// ---------------- fused per-window kernel: 12 waves == 12 heads ----------------
__global__ __launch_bounds__(768, 3) void wca_fused(
    const float* __restrict__ kv, const float* __restrict__ q,
    const float* __restrict__ b_kv, const float* __restrict__ b_q,
    const float* __restrict__ bias_table, const float* __restrict__ b_proj,
    const u16* __restrict__ wkvT, const u16* __restrict__ wqT, const u16* __restrict__ wprojT,
    float* __restrict__ out) {

    __shared__ u16 lds[LDS_TOT];

    const int tid  = threadIdx.x;
    const int b    = blockIdx.x;
    const int wave = tid >> 6, lane = tid & 63, ln = lane & 15, quad = lane >> 4;
    const int h    = wave;   // wave == head (phases 1-2); same index reused as proj n-tile

    u16* ks     = lds + OFF_KS;
    u16* vt     = lds + OFF_VT;
    u16* bias_s = lds + OFF_BIAS;
    u16* kvs    = lds + OFF_UC;                      // phase 0/1 only (aliases phase-2 bufs)
    u16* qtile  = lds + OFF_QT;
    u16* obuf   = lds + OFF_OB;
    u16* qp_s   = lds + OFF_QP + h * (16 * QP_STR);  // wave-private
    u16* P_s    = lds + OFF_P  + h * (16 * P_STR);   // wave-private

    // ---- phase 0: stage kv (49x384 fp32->bf16), bias table, zero vt ----
    {
        const float4* src = (const float4*)(kv + (size_t)b * NKV * DIM);
        for (int c = tid; c < NKV * DIM / 4; c += 768) {
            int r = c / (DIM / 4), c4 = c % (DIM / 4);
            float4 f = src[c];
            ushort4 u; u.x = f2b(f.x); u.y = f2b(f.y); u.z = f2b(f.z); u.w = f2b(f.w);
            *(ushort4*)&kvs[r * KS_STR + c4 * 4] = u;
        }
        for (int c = tid; c < 169 * NH; c += 768) bias_s[c] = f2b(bias_table[c]);
        for (int c = tid; c < NH * HD * VT_STR; c += 768) vt[c] = 0;
    }
    __syncthreads();

    // ---- phase 1: kvp for head h (M=49 pad 64, N=64 {K|V}, K=384); one wave per head ----
    {
        const int cb = h * HD;
        f32x4 acc[4][4];   // [j: n-tile (0,1=K cols; 2,3=V cols)][m: kk tile]
#pragma unroll
        for (int j = 0; j < 4; j++)
#pragma unroll
            for (int m = 0; m < 4; m++) acc[j][m] = (f32x4){0.f, 0.f, 0.f, 0.f};
        const u16* wb[4] = {
            wkvT + (size_t)(cb + ln) * DIM,
            wkvT + (size_t)(cb + 16 + ln) * DIM,
            wkvT + (size_t)(DIM + cb + ln) * DIM,
            wkvT + (size_t)(DIM + cb + 16 + ln) * DIM };
        const u16* ar[4] = {
            &kvs[imin(ln,      NKV - 1) * KS_STR],
            &kvs[imin(16 + ln, NKV - 1) * KS_STR],
            &kvs[imin(32 + ln, NKV - 1) * KS_STR],
            &kvs[imin(48 + ln, NKV - 1) * KS_STR] };
#pragma unroll
        for (int k = 0; k < 12; k++) {
            bf16x8 b0 = ld_frag(wb[0] + k * 32 + quad * 8);
            bf16x8 b1 = ld_frag(wb[1] + k * 32 + quad * 8);
            bf16x8 b2 = ld_frag(wb[2] + k * 32 + quad * 8);
            bf16x8 b3 = ld_frag(wb[3] + k * 32 + quad * 8);
#pragma unroll
            for (int m = 0; m < 4; m++) {
                bf16x8 a = ld_frag(ar[m] + k * 32 + quad * 8);
                acc[0][m] = MFMA(a, b0, acc[0][m]);
                acc[1][m] = MFMA(a, b1, acc[1][m]);
                acc[2][m] = MFMA(a, b2, acc[2][m]);
                acc[3][m] = MFMA(a, b3, acc[3][m]);
            }
        }
        float bk0 = b_kv[cb + ln],       bk1 = b_kv[cb + 16 + ln];
        float bv0 = b_kv[DIM + cb + ln], bv1 = b_kv[DIM + cb + 16 + ln];
        u16* vth = vt + h * (HD * VT_STR);
#pragma unroll
        for (int m = 0; m < 4; m++)
#pragma unroll
            for (int r = 0; r < 4; r++) {
                int kk = m * 16 + quad * 4 + r;
                if (kk < NKV) {
                    ks[kk * KS_STR + cb + ln]      = f2b(acc[0][m][r] + bk0);
                    ks[kk * KS_STR + cb + 16 + ln] = f2b(acc[1][m][r] + bk1);
                    vth[ln * VT_STR + kk]          = f2b(acc[2][m][r] + bv0);
                    vth[(16 + ln) * VT_STR + kk]   = f2b(acc[3][m][r] + bv1);
                }
            }
    }
    __syncthreads();   // kvs dead from here; phase-2 union buffers become live

    // ---- per-lane constants for phase 2 ----
    int  kterm[4];  bool kval[4];
#pragma unroll
    for (int n = 0; n < 4; n++) {
        int kk = n * 16 + ln;
        int t4 = 4 * kk, kA = t4 / 14, kB = t4 - kA * 14;
        kterm[n] = 84 - 13 * (kA >> 1) - (kB >> 1);
        kval[n]  = (kk < NKV);
    }
    const float bq0 = b_q[h * HD + ln], bq1 = b_q[h * HD + 16 + ln];
    const float bpj = b_proj[h * 16 + ln];
    const f32x4 z4 = {0.f, 0.f, 0.f, 0.f};

    // hoist w_qT fragments for this head (reused by all 13 groups)
    bf16x8 wqf[2][6];
#pragma unroll
    for (int k = 0; k < 6; k++) {
        wqf[0][k] = ld_frag(&wqT[(size_t)(h * HD + ln) * KQ + k * 32 + quad * 8]);
        wqf[1][k] = ld_frag(&wqT[(size_t)(h * HD + 16 + ln) * KQ + k * 32 + quad * 8]);
    }

    // stage q tile 0 (16x192 fp32 -> bf16); 768 threads == 768 float4s, one each
    {
        int rr = tid / 48, c4 = tid % 48;
        int qrow = imin(rr, QN - 1);
        float4 f = *(const float4*)(q + ((size_t)b * QN + qrow) * KQ + c4 * 4);
        ushort4 u; u.x = f2b(f.x); u.y = f2b(f.y); u.z = f2b(f.z); u.w = f2b(f.w);
        *(ushort4*)&qtile[rr * QT_STR + c4 * 4] = u;
    }
    __syncthreads();

    // ---- phase 2: 13 q-row groups; per group {head-parallel attention} BAR {proj} BAR ----
    for (int t = 0; t < 13; ++t) {
        // qp for this head, this 16-row tile (M=16, N=32, K=192)
        f32x4 qa0 = z4, qa1 = z4;
        {
            const u16* qrp = &qtile[ln * QT_STR + quad * 8];
#pragma unroll
            for (int k = 0; k < 6; k++) {
                bf16x8 a = ld_frag(qrp + k * 32);
                qa0 = MFMA(a, wqf[0][k], qa0);
                qa1 = MFMA(a, wqf[1][k], qa1);
            }
        }
#pragma unroll
        for (int r = 0; r < 4; r++) {
            qp_s[(quad * 4 + r) * QP_STR + ln]      = f2b((qa0[r] + bq0) * SCALE);
            qp_s[(quad * 4 + r) * QP_STR + 16 + ln] = f2b((qa1[r] + bq1) * SCALE);
        }
        lds_fence();

        // QK^T (M=16, N=64, K=32)
        bf16x8 aq = ld_frag(&qp_s[ln * QP_STR + quad * 8]);
        f32x4 s[4];
#pragma unroll
        for (int n = 0; n < 4; n++) {
            bf16x8 bk = ld_frag(&ks[imin(n * 16 + ln, NKV - 1) * KS_STR + h * HD + quad * 8]);
            s[n] = MFMA(aq, bk, z4);
        }
        // softmax (wave-private, 16-lane shuffle reduce per row)
        float rsum[4];
#pragma unroll
        for (int r = 0; r < 4; r++) {
            int qrow = t * 16 + quad * 4 + r;
            int qb = imin(qrow, QN - 1);
            int aqd = qb / 14, bqd = qb - aqd * 14;
            int qterm = 13 * (aqd >> 1) + (bqd >> 1);
            float sv[4];
#pragma unroll
            for (int n = 0; n < 4; n++) {
                if (kval[n]) sv[n] = s[n][r] + b2f(bias_s[(qterm + kterm[n]) * NH + h]);
                else         sv[n] = -1e30f;
            }
            float mx = fmaxf(fmaxf(sv[0], sv[1]), fmaxf(sv[2], sv[3]));
            mx = fmaxf(mx, __shfl_xor(mx, 1));
            mx = fmaxf(mx, __shfl_xor(mx, 2));
            mx = fmaxf(mx, __shfl_xor(mx, 4));
            mx = fmaxf(mx, __shfl_xor(mx, 8));
            float e[4], sum = 0.f;
#pragma unroll
            for (int n = 0; n < 4; n++) { e[n] = __expf(sv[n] - mx); sum += e[n]; }
            sum += __shfl_xor(sum, 1);
            sum += __shfl_xor(sum, 2);
            sum += __shfl_xor(sum, 4);
            sum += __shfl_xor(sum, 8);
            rsum[r] = sum;
#pragma unroll
            for (int n = 0; n < 4; n++)
                P_s[(quad * 4 + r) * P_STR + n * 16 + ln] = f2b(e[n]);
        }
        lds_fence();

        // PV: o = P @ V^T  (M=16, N=32, K=64); write normalized o slice to obuf[h]
        {
            bf16x8 ap0 = ld_frag(&P_s[ln * P_STR + quad * 8]);
            bf16x8 ap1 = ld_frag(&P_s[ln * P_STR + 32 + quad * 8]);
            const u16* vth = &vt[h * (HD * VT_STR)];
            bf16x8 bv00 = ld_frag(&vth[ln * VT_STR + quad * 8]);
            bf16x8 bv01 = ld_frag(&vth[ln * VT_STR + 32 + quad * 8]);
            bf16x8 bv10 = ld_frag(&vth[(16 + ln) * VT_STR + quad * 8]);
            bf16x8 bv11 = ld_frag(&vth[(16 + ln) * VT_STR + 32 + quad * 8]);
            f32x4 o0 = MFMA(ap0, bv00, z4); o0 = MFMA(ap1, bv01, o0);
            f32x4 o1 = MFMA(ap0, bv10, z4); o1 = MFMA(ap1, bv11, o1);
#pragma unroll
            for (int r = 0; r < 4; r++) {
                float rinv = 1.0f / rsum[r];
                obuf[h * 640 + (quad * 4 + r) * OB_STR + ln]      = f2b(o0[r] * rinv);
                obuf[h * 640 + (quad * 4 + r) * OB_STR + 16 + ln] = f2b(o1[r] * rinv);
            }
        }
        __syncthreads();   // all heads' o slices visible

        // stage next q tile early (global load latency hides under proj MFMAs)
        if (t < 12) {
            int rr = tid / 48, c4 = tid % 48;
            int qrow = imin((t + 1) * 16 + rr, QN - 1);
            float4 f = *(const float4*)(q + ((size_t)b * QN + qrow) * KQ + c4 * 4);
            ushort4 u; u.x = f2b(f.x); u.y = f2b(f.y); u.z = f2b(f.z); u.w = f2b(f.w);
            *(ushort4*)&qtile[rr * QT_STR + c4 * 4] = u;
        }

        // proj: wave h acts as output n-tile h (M=16, N=16, K=384 over 12 head slices)
        {
            f32x4 p0 = z4, p1 = z4;
#pragma unroll
            for (int hh = 0; hh < NH; hh += 2) {
                p0 = MFMA(ld_frag(&obuf[hh * 640 + ln * OB_STR + quad * 8]),
                          ld_frag(&wprojT[(size_t)(h * 16 + ln) * DIM + hh * HD + quad * 8]), p0);
                p1 = MFMA(ld_frag(&obuf[(hh + 1) * 640 + ln * OB_STR + quad * 8]),
                          ld_frag(&wprojT[(size_t)(h * 16 + ln) * DIM + (hh + 1) * HD + quad * 8]), p1);
            }
#pragma unroll
            for (int r = 0; r < 4; r++) {
                int qrow = t * 16 + quad * 4 + r;
                if (qrow < QN)
                    out[((size_t)b * QN + qrow) * KQ + h * 16 + ln] = p0[r] + p1[r] + bpj;
            }
        }
        __syncthreads();   // proj reads done; obuf/qtile reusable next group
    }
}

extern "C" void kernel_launch(void* const* d_in, const int* in_sizes, int n_in,
                              void* d_out, int out_size, void* d_ws, size_t ws_size,
                              hipStream_t stream) {
    (void)in_sizes; (void)n_in; (void)out_size; (void)ws_size;
    const float* kv         = (const float*)d_in[0];
    const float* q          = (const float*)d_in[1];
    const float* w_kv       = (const float*)d_in[2];
    const float* b_kv       = (const float*)d_in[3];
    const float* w_q        = (const float*)d_in[4];
    const float* b_q        = (const float*)d_in[5];
    const float* bias_table = (const float*)d_in[6];
    const float* w_proj     = (const float*)d_in[7];
    const float* b_proj     = (const float*)d_in[8];
    float* out = (float*)d_out;
    u16* wbuf = (u16*)d_ws;   // 442368 ushorts = 884736 B

    prep_weights<<<864, 512, 0, stream>>>(w_kv, w_q, w_proj, wbuf);
    wca_fused<<<BWIN, 768, 0, stream>>>(kv, q, b_kv, b_q, bias_table, b_proj,
                                        wbuf, wbuf + 294912, wbuf + 368640, out);
}